// Round 4
// baseline (272.486 us; speedup 1.0000x reference)
//
#include <hip/hip_runtime.h>

// ---------------------------------------------------------------------------
// GPT-2 attention block on MI355X (gfx950), bf16-MFMA pipeline, fp32 I/O.
//   S=2048 queries, P=2048 past, T=4096 total keys, E=1024, H=16, D=64.
// R3: (a) k_attn: Pl XOR-swizzled stride-128 (kills 8-way P-read conflict),
//     exp2-domain softmax (q pre-scaled by 0.125*log2e), defer-max THR=0,
//     max3-friendly reduction tree. (b) k_gemm: double-buffered LDS with
//     prefetch-before-compute (T3 minimum 2-phase) to hide load latency.
// ---------------------------------------------------------------------------

#define SDIM 2048
#define PDIM 2048
#define TDIM 4096
#define EDIM 1024
#define HNUM 16
#define DDIM 64

typedef short bf16x8 __attribute__((ext_vector_type(8)));   // 8 bf16 (4 VGPRs)
typedef float f32x4 __attribute__((ext_vector_type(4)));
typedef unsigned int u32x2 __attribute__((ext_vector_type(2)));

__device__ __forceinline__ unsigned short f2bf(float f) {
    union { float f; unsigned u; } v; v.f = f;
    unsigned r = v.u + 0x7fffu + ((v.u >> 16) & 1u);        // RNE
    return (unsigned short)(r >> 16);
}

__device__ __forceinline__ void async16(const void* g, void* l) {
    __builtin_amdgcn_global_load_lds(
        (const __attribute__((address_space(1))) void*)g,
        (__attribute__((address_space(3))) void*)l, 16, 0, 0);
}

// --------------------------- prep kernels ----------------------------------

__global__ __launch_bounds__(256) void k_cvt_x(const float* __restrict__ in,
                                               short* __restrict__ out) {
    int i = (blockIdx.x * 256 + threadIdx.x) * 4;
    f32x4 v = *(const f32x4*)(in + i);
    unsigned lo = f2bf(v[0]) | ((unsigned)f2bf(v[1]) << 16);
    unsigned hi = f2bf(v[2]) | ((unsigned)f2bf(v[3]) << 16);
    u32x2 p = {lo, hi};
    *(u32x2*)(out + i) = p;
}

// in [R][C] fp32 -> out [C][R] bf16
__global__ __launch_bounds__(256) void k_tr_cvt(const float* __restrict__ in,
                                                short* __restrict__ out,
                                                int R, int C) {
    __shared__ float tile[32][33];
    int cb = blockIdx.x * 32, rb = blockIdx.y * 32;
    int c = threadIdx.x & 31, r0 = threadIdx.x >> 5;
#pragma unroll
    for (int i = 0; i < 4; ++i)
        tile[r0 + 8 * i][c] = in[(rb + r0 + 8 * i) * C + cb + c];
    __syncthreads();
#pragma unroll
    for (int i = 0; i < 4; ++i)
        out[(cb + r0 + 8 * i) * R + rb + c] = (short)f2bf(tile[c][r0 + 8 * i]);
}

// past_key [H][P][D] -> present_k fp32 [H][T][D] (t<P) + Kb bf16 same layout
__global__ __launch_bounds__(256) void k_past_key(const float* __restrict__ pk,
                                                  short* __restrict__ Kb,
                                                  float* __restrict__ pk_out) {
    int i = (blockIdx.x * 256 + threadIdx.x) * 4;   // over H*P*D = 2M
    int h = i >> 17;                                // P*D = 131072
    f32x4 v = *(const f32x4*)(pk + i);
    int dst = i + (h << 17);                        // [H][T][D], first half
    *(f32x4*)(pk_out + dst) = v;
    unsigned lo = f2bf(v[0]) | ((unsigned)f2bf(v[1]) << 16);
    unsigned hi = f2bf(v[2]) | ((unsigned)f2bf(v[3]) << 16);
    u32x2 p = {lo, hi};
    *(u32x2*)(Kb + dst) = p;
}

// past_value [H][P][D] -> present_v fp32 + Vt bf16 [H][D][T] (transposed)
__global__ __launch_bounds__(256) void k_past_value(const float* __restrict__ pv,
                                                    short* __restrict__ Vt,
                                                    float* __restrict__ pv_out) {
    __shared__ float tile[32][33];
    int h = blockIdx.z;
    int tb = blockIdx.x * 32;   // t
    int db = blockIdx.y * 32;   // d
    int c = threadIdx.x & 31, r0 = threadIdx.x >> 5;
    const float* src = pv + (h << 17);
    float* dst = pv_out + (h << 18);
#pragma unroll
    for (int i = 0; i < 4; ++i) {
        int r = r0 + 8 * i;
        float v = src[(tb + r) * DDIM + db + c];
        tile[r][c] = v;
        dst[(tb + r) * DDIM + db + c] = v;
    }
    __syncthreads();
#pragma unroll
    for (int i = 0; i < 4; ++i) {
        int d = r0 + 8 * i;
        Vt[(h * DDIM + db + d) * TDIM + tb + c] = (short)f2bf(tile[c][d]);
    }
}

// --------------------------- GEMM (m97 + T3 2-phase) -----------------------
// A [M][K] bf16, Bt [N][K] bf16 (pre-transposed). 128x128 tile, BK=32,
// 256 thr = 4 waves (2x2 of 64x64), 16x16x32 MFMA. Double-buffered LDS:
// issue next K-tile's global_load_lds BEFORE current tile's ds_read+MFMA
// so the ~300cy load latency hides under compute; one barrier per iter.
// MODE 0: QKV epilogue (q_ws/Kb/Vt/present). MODE 1: proj -> fp32 out + bias.

#define QSCALE 0.1803368801f   // 0.125 * log2(e): exp2-domain softmax

template <int MODE>
__global__ __launch_bounds__(256) void k_gemm(
    const short* __restrict__ A, const short* __restrict__ Bt,
    const float* __restrict__ bias, int K,
    short* __restrict__ q_ws, short* __restrict__ Kb, short* __restrict__ Vt,
    float* __restrict__ pk, float* __restrict__ pv,
    float* __restrict__ outF, int N) {
    __shared__ short As[2][128 * 32];
    __shared__ short Bs[2][128 * 32];
    const int tid = threadIdx.x;
    const int m0 = blockIdx.y * 128, n0 = blockIdx.x * 128;
    const int w = tid >> 6, lane = tid & 63;
    const int wm = w >> 1, wn = w & 1;
    const int l15 = lane & 15, g = lane >> 4;

    f32x4 zero = {0.f, 0.f, 0.f, 0.f};
    f32x4 acc[4][4];
#pragma unroll
    for (int i = 0; i < 4; ++i)
#pragma unroll
        for (int j = 0; j < 4; ++j) acc[i][j] = zero;

    const int arow = tid >> 2;
    const int acol = (tid & 3) << 3;
    const short* Ab  = A  + (m0 + arow) * K + acol;
    const short* Ab2 = A  + (m0 + 64 + arow) * K + acol;
    const short* Bb  = Bt + (n0 + arow) * K + acol;
    const short* Bb2 = Bt + (n0 + 64 + arow) * K + acol;

    const int aoff = (wm * 64 + l15) * 32 + g * 8;
    const int boff = (wn * 64 + l15) * 32 + g * 8;

    auto stage = [&](int buf, int kt) {
        async16(Ab + kt,  &As[buf][tid * 8]);
        async16(Ab2 + kt, &As[buf][2048 + tid * 8]);
        async16(Bb + kt,  &Bs[buf][tid * 8]);
        async16(Bb2 + kt, &Bs[buf][2048 + tid * 8]);
    };

    stage(0, 0);
    __syncthreads();                        // vmcnt(0) drained by barrier
    int cur = 0;
    for (int kt = 0; kt < K; kt += 32) {
        if (kt + 32 < K) stage(cur ^ 1, kt + 32);   // prefetch next K-tile
        bf16x8 af[4], bfr[4];
#pragma unroll
        for (int f = 0; f < 4; ++f) af[f]  = *(const bf16x8*)&As[cur][aoff + f * 512];
#pragma unroll
        for (int f = 0; f < 4; ++f) bfr[f] = *(const bf16x8*)&Bs[cur][boff + f * 512];
#pragma unroll
        for (int i = 0; i < 4; ++i)
#pragma unroll
            for (int j = 0; j < 4; ++j)
                acc[i][j] = __builtin_amdgcn_mfma_f32_16x16x32_bf16(
                    af[i], bfr[j], acc[i][j], 0, 0, 0);
        __syncthreads();                    // drains prefetch + compute
        cur ^= 1;
    }

    // Epilogue: C[row][col], row = m0+wm*64+i*16+4g+r, col = n0+wn*64+j*16+l15
    if (MODE == 1) {
#pragma unroll
        for (int j = 0; j < 4; ++j) {
            int ncol = n0 + wn * 64 + j * 16 + l15;
            float b = bias[ncol];
#pragma unroll
            for (int i = 0; i < 4; ++i) {
                int mb = m0 + wm * 64 + i * 16 + g * 4;
#pragma unroll
                for (int r = 0; r < 4; ++r)
                    outF[(mb + r) * N + ncol] = acc[i][j][r] + b;
            }
        }
    } else {
        const int sec = n0 >> 10;   // 0=q 1=k 2=v (uniform per block)
#pragma unroll
        for (int j = 0; j < 4; ++j) {
            int ncol = n0 + wn * 64 + j * 16 + l15;
            float b = bias[ncol];
            int h = (ncol >> 6) & 15;
            int d = ncol & 63;
#pragma unroll
            for (int i = 0; i < 4; ++i) {
                int mb = m0 + wm * 64 + i * 16 + g * 4;
#pragma unroll
                for (int r = 0; r < 4; ++r) {
                    int s = mb + r;
                    float val = acc[i][j][r] + b;
                    if (sec == 0) {
                        q_ws[(h * SDIM + s) * DDIM + d] = (short)f2bf(val * QSCALE);
                    } else if (sec == 1) {
                        int idx = (h * TDIM + PDIM + s) * DDIM + d;
                        pk[idx] = val;
                        Kb[idx] = (short)f2bf(val);
                    } else {
                        pv[(h * TDIM + PDIM + s) * DDIM + d] = val;
                        Vt[(h * DDIM + d) * TDIM + PDIM + s] = (short)f2bf(val);
                    }
                }
            }
        }
    }
}

// --------------------------- flash attention -------------------------------
// Block: h = bid&15 (XCD n hosts heads n, n+8 -> 4MB K+V = one L2).
// qt remapped for load balance (ntiles = 33+qt): adjacent blocks pair i, 31-i.
// 4 waves x 16 q-rows, 64-key tiles. K/V staged in LDS via global_load_lds
// (16B), double-buffered, XOR-swizzled via pre-swizzled source (rule #21).
// Swapped QK^T: S^T = mfma(K, Q). Softmax in exp2 domain (q pre-scaled by
// log2e). P buffer: [16][64] stride-128B, col ^ ((row&7)<<4) swizzle ->
// reads at the 8-words/bank floor (was 8-way conflict). Defer-max THR=0.
__global__ __launch_bounds__(256) void k_attn(const short* __restrict__ q_ws,
                                              const short* __restrict__ Kb,
                                              const short* __restrict__ Vt,
                                              short* __restrict__ aout) {
    __shared__ short Ks[2][64 * 64];   // [buf][row=key][d]  (swizzled layout)
    __shared__ short Vs[2][64 * 64];   // [buf][row=d][t]    (swizzled layout)
    __shared__ short Pl[4][16][64];    // per wave, stride 128B, XOR-swizzled
    const int tid = threadIdx.x;
    const int w = tid >> 6, lane = tid & 63;
    const int l15 = lane & 15, g = lane >> 4;
    const int h = blockIdx.x & 15;
    const int j = blockIdx.x >> 4;
    const int qt = (j & 1) ? (31 - (j >> 1)) : (j >> 1);   // balance pairing
    const int q = qt * 64 + w * 16 + l15;   // this lane's q row

    const short* qb = q_ws + (h * SDIM + q) * DDIM;   // pre-scaled by QSCALE
    bf16x8 bq0 = *(const bf16x8*)(qb + g * 8);
    bf16x8 bq1 = *(const bf16x8*)(qb + 32 + g * 8);

    const short* Kh = Kb + h * TDIM * DDIM;
    const short* Vh = Vt + h * DDIM * TDIM;

    f32x4 zero = {0.f, 0.f, 0.f, 0.f};
    f32x4 o[4] = {zero, zero, zero, zero};
    float m_run = -1e30f, l_run = 0.f;
    const int ntiles = 33 + qt;             // exactly covers keys <= P+q0+63
    char* myP = (char*)&Pl[w][0][0];
    const int pswz = (l15 & 7) << 4;        // P-buffer col XOR (bits 4..6)
    const int r7 = pswz;                    // K/V read-side XOR

    // stage one 64-key K tile + V tile into buffer `buf`; wave w covers
    // bytes [w*1024 + i*4096 .. +1024) of each 8KB tile; source pre-swizzled.
    auto stage = [&](int buf, int t) {
        const int t0 = t * 64;
        const char* Kg = (const char*)(Kh + t0 * DDIM);   // contiguous 8KB
        const char* Vg = (const char*)(Vh + t0);          // rows of 128B, stride 8192B
#pragma unroll
        for (int i = 0; i < 2; ++i) {
            int b = w * 1024 + i * 4096 + (lane << 4);    // dest byte in tile
            int sb = b ^ (((b >> 7) & 7) << 4);           // swizzled source byte
            async16(Kg + sb, (char*)&Ks[buf][0] + w * 1024 + i * 4096);
            int vrow = b >> 7;
            int vcol = (b & 127) ^ ((vrow & 7) << 4);
            async16(Vg + vrow * (TDIM * 2) + vcol,
                    (char*)&Vs[buf][0] + w * 1024 + i * 4096);
        }
    };

    int cur = 0;
    stage(0, 0);
    __syncthreads();                         // drains vmcnt + lgkm

    for (int t = 0; t < ntiles; ++t) {
        const int t0 = t * 64;
        if (t + 1 < ntiles) stage(cur ^ 1, t + 1);   // prefetch next tile

        const char* Kc = (const char*)&Ks[cur][0];
        const char* Vc = (const char*)&Vs[cur][0];

        f32x4 sc[4];
#pragma unroll
        for (int kb = 0; kb < 4; ++kb) {    // S^T[key][q], log2 domain
            const char* kr = Kc + (kb * 16 + l15) * 128;
            bf16x8 ak0 = *(const bf16x8*)(kr + ((g * 16) ^ r7));
            bf16x8 ak1 = *(const bf16x8*)(kr + ((64 + g * 16) ^ r7));
            f32x4 c = zero;
            c = __builtin_amdgcn_mfma_f32_16x16x32_bf16(ak0, bq0, c, 0, 0, 0);
            c = __builtin_amdgcn_mfma_f32_16x16x32_bf16(ak1, bq1, c, 0, 0, 0);
            sc[kb] = c;
        }
        if (t == ntiles - 1) {              // causal mask, last tile only
#pragma unroll
            for (int kb = 0; kb < 4; ++kb)
#pragma unroll
                for (int i = 0; i < 4; ++i)
                    if (t0 + kb * 16 + g * 4 + i > PDIM + q) sc[kb][i] = -1e30f;
        }
        // per-q-row max (lanes l15, l15+16, l15+32, l15+48 share a q-row)
        float t01 = fmaxf(fmaxf(sc[0][0], sc[0][1]), fmaxf(sc[0][2], sc[0][3]));
        float t23 = fmaxf(fmaxf(sc[1][0], sc[1][1]), fmaxf(sc[1][2], sc[1][3]));
        float t45 = fmaxf(fmaxf(sc[2][0], sc[2][1]), fmaxf(sc[2][2], sc[2][3]));
        float t67 = fmaxf(fmaxf(sc[3][0], sc[3][1]), fmaxf(sc[3][2], sc[3][3]));
        float tmax = fmaxf(fmaxf(t01, t23), fmaxf(t45, t67));
        tmax = fmaxf(tmax, __shfl_xor(tmax, 16));
        tmax = fmaxf(tmax, __shfl_xor(tmax, 32));
        // defer-max THR=0: skip (exactly-equivalent) rescale when no growth
        if (!__all(tmax <= m_run)) {
            float m_new = fmaxf(m_run, tmax);
            float scale = exp2f(m_run - m_new);
            l_run *= scale;
#pragma unroll
            for (int d = 0; d < 4; ++d) o[d] *= scale;
            m_run = m_new;
        }
        float psum = 0.f;
        unsigned pw[8];
#pragma unroll
        for (int kb = 0; kb < 4; ++kb) {
            float p0 = exp2f(sc[kb][0] - m_run);
            float p1 = exp2f(sc[kb][1] - m_run);
            float p2 = exp2f(sc[kb][2] - m_run);
            float p3 = exp2f(sc[kb][3] - m_run);
            psum += (p0 + p1) + (p2 + p3);
            asm("v_cvt_pk_bf16_f32 %0, %1, %2"
                : "=v"(pw[2 * kb]) : "v"(p0), "v"(p1));
            asm("v_cvt_pk_bf16_f32 %0, %1, %2"
                : "=v"(pw[2 * kb + 1]) : "v"(p2), "v"(p3));
        }
        psum += __shfl_xor(psum, 16);
        psum += __shfl_xor(psum, 32);
        l_run += psum;
#pragma unroll
        for (int kb = 0; kb < 4; ++kb) {    // P[q][key], 8B, swizzled col
            u32x2 pk2 = {pw[2 * kb], pw[2 * kb + 1]};
            *(u32x2*)(myP + l15 * 128 + ((kb * 32 + g * 8) ^ pswz)) = pk2;
        }
        asm volatile("s_waitcnt lgkmcnt(0)" ::: "memory");
        __builtin_amdgcn_sched_barrier(0);
        bf16x8 bp0 = *(const bf16x8*)(myP + l15 * 128 + ((g * 16) ^ pswz));
        bf16x8 bp1 = *(const bf16x8*)(myP + l15 * 128 + ((64 + g * 16) ^ pswz));
#pragma unroll
        for (int d = 0; d < 4; ++d) {       // O^T[d][q] += V^T . P^T
            const char* vr = Vc + (d * 16 + l15) * 128;
            bf16x8 av0 = *(const bf16x8*)(vr + ((g * 16) ^ r7));
            bf16x8 av1 = *(const bf16x8*)(vr + ((64 + g * 16) ^ r7));
            o[d] = __builtin_amdgcn_mfma_f32_16x16x32_bf16(av0, bp0, o[d], 0, 0, 0);
            o[d] = __builtin_amdgcn_mfma_f32_16x16x32_bf16(av1, bp1, o[d], 0, 0, 0);
        }
        __syncthreads();                    // drains vmcnt (prefetch) + compute
        cur ^= 1;
    }
    float inv = 1.0f / l_run;
#pragma unroll
    for (int d = 0; d < 4; ++d) {
        unsigned lo = f2bf(o[d][0] * inv) | ((unsigned)f2bf(o[d][1] * inv) << 16);
        unsigned hi = f2bf(o[d][2] * inv) | ((unsigned)f2bf(o[d][3] * inv) << 16);
        u32x2 pk2 = {lo, hi};
        *(u32x2*)(aout + q * EDIM + h * DDIM + d * 16 + g * 4) = pk2;
    }
}

// --------------------------- launch ----------------------------------------

extern "C" void kernel_launch(void* const* d_in, const int* in_sizes, int n_in,
                              void* d_out, int out_size, void* d_ws, size_t ws_size,
                              hipStream_t stream) {
    const float* x          = (const float*)d_in[0];
    const float* past_key   = (const float*)d_in[1];
    const float* past_value = (const float*)d_in[2];
    // d_in[3] = mask: recomputed analytically (k <= q + P)
    const float* c_attn_w   = (const float*)d_in[4];
    const float* c_attn_b   = (const float*)d_in[5];
    const float* c_proj_w   = (const float*)d_in[6];
    const float* c_proj_b   = (const float*)d_in[7];

    float* out_a  = (float*)d_out;
    float* pk_out = out_a + (size_t)SDIM * EDIM;           // present[0]
    float* pv_out = pk_out + (size_t)HNUM * TDIM * DDIM;   // present[1]

    char* ws = (char*)d_ws;
    short* xb     = (short*)(ws);                //  4 MB
    short* wqkvt  = (short*)(ws + (4u  << 20));  //  6 MB  [3E][E]
    short* wprojt = (short*)(ws + (10u << 20));  //  2 MB  [E][E]
    short* q_ws   = (short*)(ws + (12u << 20));  //  4 MB  [H][S][D] *QSCALE
    short* Kb     = (short*)(ws + (16u << 20));  //  8 MB  [H][T][D]
    short* Vt     = (short*)(ws + (24u << 20));  //  8 MB  [H][D][T]
    short* aout   = (short*)(ws + (32u << 20));  //  4 MB  [S][E]

    k_cvt_x<<<2048, 256, 0, stream>>>(x, xb);
    k_tr_cvt<<<dim3(96, 32), 256, 0, stream>>>(c_attn_w, wqkvt, EDIM, 3 * EDIM);
    k_tr_cvt<<<dim3(32, 32), 256, 0, stream>>>(c_proj_w, wprojt, EDIM, EDIM);
    k_past_key<<<2048, 256, 0, stream>>>(past_key, Kb, pk_out);
    k_past_value<<<dim3(64, 2, 16), 256, 0, stream>>>(past_value, Vt, pv_out);

    k_gemm<0><<<dim3(24, 16), 256, 0, stream>>>(
        xb, wqkvt, c_attn_b, EDIM, q_ws, Kb, Vt, pk_out, pv_out,
        (float*)nullptr, 3 * EDIM);

    k_attn<<<512, 256, 0, stream>>>(q_ws, Kb, Vt, aout);

    k_gemm<1><<<dim3(8, 16), 256, 0, stream>>>(
        aout, wprojt, c_proj_b, EDIM,
        (short*)nullptr, (short*)nullptr, (short*)nullptr,
        (float*)nullptr, (float*)nullptr, out_a, EDIM);
}

// Round 9
// 230.382 us; speedup vs baseline: 1.1828x; 1.1828x over previous
//
#include <hip/hip_runtime.h>

// ---------------------------------------------------------------------------
// GPT-2 attention block on MI355X (gfx950), bf16-MFMA pipeline, fp32 I/O.
//   S=2048 queries, P=2048 past, T=4096 total keys, E=1024, H=16, D=64.
// R8 (= R4..R7 resubmit; four GPU-acquisition timeouts, still unmeasured):
//   (a) k_attn_part: no-max exp2 softmax (branch-free loop), l via all-ones
//       MFMA, KV-split x2 -> grid 1024 = 4 blocks/CU (LDS-exact 40960B).
//   (b) fused prep (5 kernels -> 1 range-dispatched launch).
//   (c) ws fits in 32 MB: po1 -> d_out's `a` region (dead until gemm1),
//       aout overlays dead q_ws, pl overlays dead wqkvt tail.
// ws layout: [0,4) xb | [4,10) wqkvt   (both dead after gemm0)
//            [0,8) po0 (overlay) | [8.5,8.75) pl (overlay)
//            [10,12) wprojt | [12,16) q_ws -> aout (overlay after attn)
//            [16,24) Kb | [24,32) Vt.        po1 = d_out[0:8MB).
// ---------------------------------------------------------------------------

#define SDIM 2048
#define PDIM 2048
#define TDIM 4096
#define EDIM 1024
#define HNUM 16
#define DDIM 64

typedef short bf16x8 __attribute__((ext_vector_type(8)));   // 8 bf16 (4 VGPRs)
typedef float f32x4 __attribute__((ext_vector_type(4)));
typedef unsigned int u32x2 __attribute__((ext_vector_type(2)));

#define QSCALE 0.1803368801f   // 0.125 * log2(e): exp2-domain softmax

__device__ __forceinline__ unsigned short f2bf(float f) {
    union { float f; unsigned u; } v; v.f = f;
    unsigned r = v.u + 0x7fffu + ((v.u >> 16) & 1u);        // RNE
    return (unsigned short)(r >> 16);
}

__device__ __forceinline__ float fexp2(float x) {           // v_exp_f32 = 2^x
    float r;
    asm("v_exp_f32 %0, %1" : "=v"(r) : "v"(x));
    return r;
}

__device__ __forceinline__ void async16(const void* g, void* l) {
    __builtin_amdgcn_global_load_lds(
        (const __attribute__((address_space(1))) void*)g,
        (__attribute__((address_space(3))) void*)l, 16, 0, 0);
}

// --------------------------- fused prep ------------------------------------
// Range-dispatched: [0,2048) cvt_x | [2048,5120) tr c_attn_w |
// [5120,6144) tr c_proj_w | [6144,8192) past_key | [8192,10240) past_value.
__global__ __launch_bounds__(256) void k_prep(
    const float* __restrict__ x, const float* __restrict__ pk_in,
    const float* __restrict__ pv_in, const float* __restrict__ c_attn_w,
    const float* __restrict__ c_proj_w,
    short* __restrict__ xb, short* __restrict__ wqkvt,
    short* __restrict__ wprojt, short* __restrict__ Kb,
    short* __restrict__ Vt, float* __restrict__ pk_out,
    float* __restrict__ pv_out) {
    __shared__ float tile[32][33];
    const int bid = blockIdx.x, tid = threadIdx.x;

    if (bid < 2048) {                       // x -> bf16
        int i = (bid * 256 + tid) * 4;
        f32x4 v = *(const f32x4*)(x + i);
        unsigned lo = f2bf(v[0]) | ((unsigned)f2bf(v[1]) << 16);
        unsigned hi = f2bf(v[2]) | ((unsigned)f2bf(v[3]) << 16);
        u32x2 p = {lo, hi};
        *(u32x2*)(xb + i) = p;
    } else if (bid < 8192) {                // transpose+convert weights
        const float* in; short* out; int R, C, cb, rb;
        if (bid < 5120) {
            int u = bid - 2048;
            in = c_attn_w; out = wqkvt; R = EDIM; C = 3 * EDIM;
            cb = (u % 96) * 32; rb = (u / 96) * 32;
        } else if (bid < 6144) {
            int u = bid - 5120;
            in = c_proj_w; out = wprojt; R = EDIM; C = EDIM;
            cb = (u & 31) * 32; rb = (u >> 5) * 32;
        } else {                            // past_key copy+convert
            int u = bid - 6144;
            int i = (u * 256 + tid) * 4;    // over H*P*D = 2M
            int h = i >> 17;
            f32x4 v = *(const f32x4*)(pk_in + i);
            int dst = i + (h << 17);        // [H][T][D], first half
            *(f32x4*)(pk_out + dst) = v;
            unsigned lo = f2bf(v[0]) | ((unsigned)f2bf(v[1]) << 16);
            unsigned hi = f2bf(v[2]) | ((unsigned)f2bf(v[3]) << 16);
            u32x2 p = {lo, hi};
            *(u32x2*)(Kb + dst) = p;
            return;
        }
        int c = tid & 31, r0 = tid >> 5;
#pragma unroll
        for (int i = 0; i < 4; ++i)
            tile[r0 + 8 * i][c] = in[(rb + r0 + 8 * i) * C + cb + c];
        __syncthreads();
#pragma unroll
        for (int i = 0; i < 4; ++i)
            out[(cb + r0 + 8 * i) * R + rb + c] = (short)f2bf(tile[c][r0 + 8 * i]);
    } else {                                // past_value -> fp32 + Vt bf16^T
        int u = bid - 8192;
        int h = u >> 7;
        int tb = (u & 63) * 32;
        int db = ((u >> 6) & 1) * 32;
        int c = tid & 31, r0 = tid >> 5;
        const float* src = pv_in + (h << 17);
        float* dst = pv_out + (h << 18);
#pragma unroll
        for (int i = 0; i < 4; ++i) {
            int r = r0 + 8 * i;
            float v = src[(tb + r) * DDIM + db + c];
            tile[r][c] = v;
            dst[(tb + r) * DDIM + db + c] = v;
        }
        __syncthreads();
#pragma unroll
        for (int i = 0; i < 4; ++i) {
            int d = r0 + 8 * i;
            Vt[(h * DDIM + db + d) * TDIM + tb + c] = (short)f2bf(tile[c][d]);
        }
    }
}

// --------------------------- GEMM (m97 + 2-phase dbuf) ---------------------
template <int MODE>
__global__ __launch_bounds__(256) void k_gemm(
    const short* __restrict__ A, const short* __restrict__ Bt,
    const float* __restrict__ bias, int K,
    short* __restrict__ q_ws, short* __restrict__ Kb, short* __restrict__ Vt,
    float* __restrict__ pk, float* __restrict__ pv,
    float* __restrict__ outF, int N) {
    __shared__ short As[2][128 * 32];
    __shared__ short Bs[2][128 * 32];
    const int tid = threadIdx.x;
    const int m0 = blockIdx.y * 128, n0 = blockIdx.x * 128;
    const int w = tid >> 6, lane = tid & 63;
    const int wm = w >> 1, wn = w & 1;
    const int l15 = lane & 15, g = lane >> 4;

    f32x4 zero = {0.f, 0.f, 0.f, 0.f};
    f32x4 acc[4][4];
#pragma unroll
    for (int i = 0; i < 4; ++i)
#pragma unroll
        for (int j = 0; j < 4; ++j) acc[i][j] = zero;

    const int arow = tid >> 2;
    const int acol = (tid & 3) << 3;
    const short* Ab  = A  + (m0 + arow) * K + acol;
    const short* Ab2 = A  + (m0 + 64 + arow) * K + acol;
    const short* Bb  = Bt + (n0 + arow) * K + acol;
    const short* Bb2 = Bt + (n0 + 64 + arow) * K + acol;

    const int aoff = (wm * 64 + l15) * 32 + g * 8;
    const int boff = (wn * 64 + l15) * 32 + g * 8;

    auto stage = [&](int buf, int kt) {
        async16(Ab + kt,  &As[buf][tid * 8]);
        async16(Ab2 + kt, &As[buf][2048 + tid * 8]);
        async16(Bb + kt,  &Bs[buf][tid * 8]);
        async16(Bb2 + kt, &Bs[buf][2048 + tid * 8]);
    };

    stage(0, 0);
    __syncthreads();
    int cur = 0;
    for (int kt = 0; kt < K; kt += 32) {
        if (kt + 32 < K) stage(cur ^ 1, kt + 32);   // prefetch next K-tile
        bf16x8 af[4], bfr[4];
#pragma unroll
        for (int f = 0; f < 4; ++f) af[f]  = *(const bf16x8*)&As[cur][aoff + f * 512];
#pragma unroll
        for (int f = 0; f < 4; ++f) bfr[f] = *(const bf16x8*)&Bs[cur][boff + f * 512];
#pragma unroll
        for (int i = 0; i < 4; ++i)
#pragma unroll
            for (int j = 0; j < 4; ++j)
                acc[i][j] = __builtin_amdgcn_mfma_f32_16x16x32_bf16(
                    af[i], bfr[j], acc[i][j], 0, 0, 0);
        __syncthreads();
        cur ^= 1;
    }

    if (MODE == 1) {
#pragma unroll
        for (int j = 0; j < 4; ++j) {
            int ncol = n0 + wn * 64 + j * 16 + l15;
            float b = bias[ncol];
#pragma unroll
            for (int i = 0; i < 4; ++i) {
                int mb = m0 + wm * 64 + i * 16 + g * 4;
#pragma unroll
                for (int r = 0; r < 4; ++r)
                    outF[(mb + r) * N + ncol] = acc[i][j][r] + b;
            }
        }
    } else {
        const int sec = n0 >> 10;   // 0=q 1=k 2=v (uniform per block)
#pragma unroll
        for (int j = 0; j < 4; ++j) {
            int ncol = n0 + wn * 64 + j * 16 + l15;
            float b = bias[ncol];
            int h = (ncol >> 6) & 15;
            int d = ncol & 63;
#pragma unroll
            for (int i = 0; i < 4; ++i) {
                int mb = m0 + wm * 64 + i * 16 + g * 4;
#pragma unroll
                for (int r = 0; r < 4; ++r) {
                    int s = mb + r;
                    float val = acc[i][j][r] + b;
                    if (sec == 0) {
                        q_ws[(h * SDIM + s) * DDIM + d] = (short)f2bf(val * QSCALE);
                    } else if (sec == 1) {
                        int idx = (h * TDIM + PDIM + s) * DDIM + d;
                        pk[idx] = val;
                        Kb[idx] = (short)f2bf(val);
                    } else {
                        pv[(h * TDIM + PDIM + s) * DDIM + d] = val;
                        Vt[(h * DDIM + d) * TDIM + PDIM + s] = (short)f2bf(val);
                    }
                }
            }
        }
    }
}

// --------------------------- flash attention (partials) --------------------
// grid 1024: h = bid&15; u = bid>>4: qtp = u>>1 (pairing-remapped), half=u&1.
// Each block does its half of the key range for (h, qt); no-max exp2 softmax
// makes partials additive: po = sum(P.V), pl = sum(P) (via all-ones MFMA).
// 4 waves x 16 q-rows; K/V LDS-staged (global_load_lds, pre-swizzled source),
// double-buffered; branch-free inner loop. LDS 40960B = exactly 4 blocks/CU.
__global__ __launch_bounds__(256) void k_attn_part(
    const short* __restrict__ q_ws, const short* __restrict__ Kb,
    const short* __restrict__ Vt, float* __restrict__ po0,
    float* __restrict__ po1, float* __restrict__ pl) {
    __shared__ short Ks[2][64 * 64];   // [buf][key][d]   (swizzled layout)
    __shared__ short Vs[2][64 * 64];   // [buf][d][t]     (swizzled layout)
    __shared__ short Pl[4][16][64];    // per wave, stride 128B, XOR-swizzled
    const int tid = threadIdx.x;
    const int w = tid >> 6, lane = tid & 63;
    const int l15 = lane & 15, g = lane >> 4;
    const int h = blockIdx.x & 15;
    const int u = blockIdx.x >> 4;
    const int qtp = u >> 1, half = u & 1;
    const int qt = (qtp & 1) ? (31 - (qtp >> 1)) : (qtp >> 1);   // balance
    const int q = qt * 64 + w * 16 + l15;   // this lane's q row
    const int ntot = 33 + qt;               // total key tiles for this qt
    const int t_begin = half ? (ntot >> 1) : 0;
    const int t_end   = half ? ntot : (ntot >> 1);

    const short* qb = q_ws + (h * SDIM + q) * DDIM;   // pre-scaled by QSCALE
    bf16x8 bq0 = *(const bf16x8*)(qb + g * 8);
    bf16x8 bq1 = *(const bf16x8*)(qb + 32 + g * 8);

    const short* Kh = Kb + h * TDIM * DDIM;
    const short* Vh = Vt + h * DDIM * TDIM;

    f32x4 zero = {0.f, 0.f, 0.f, 0.f};
    f32x4 o[4] = {zero, zero, zero, zero};
    f32x4 lsum = zero;                      // row-sum of P via all-ones MFMA
    const bf16x8 vones = {16256, 16256, 16256, 16256,
                          16256, 16256, 16256, 16256};   // bf16 1.0 x8
    char* myP = (char*)&Pl[w][0][0];
    const int pswz = (l15 & 7) << 4;        // XOR swizzle bits 4..6
    const int r7 = pswz;

    auto stage = [&](int buf, int t) {
        const int t0 = t * 64;
        const char* Kg = (const char*)(Kh + t0 * DDIM);   // contiguous 8KB
        const char* Vg = (const char*)(Vh + t0);          // 128B rows, 8KB stride
#pragma unroll
        for (int i = 0; i < 2; ++i) {
            int b = w * 1024 + i * 4096 + (lane << 4);    // dest byte in tile
            int sb = b ^ (((b >> 7) & 7) << 4);           // pre-swizzled source
            async16(Kg + sb, (char*)&Ks[buf][0] + w * 1024 + i * 4096);
            int vrow = b >> 7;
            int vcol = (b & 127) ^ ((vrow & 7) << 4);
            async16(Vg + vrow * (TDIM * 2) + vcol,
                    (char*)&Vs[buf][0] + w * 1024 + i * 4096);
        }
    };

    int cur = 0;
    stage(0, t_begin);
    __syncthreads();

    for (int t = t_begin; t < t_end; ++t) {
        if (t + 1 < t_end) stage(cur ^ 1, t + 1);   // prefetch next tile

        const char* Kc = (const char*)&Ks[cur][0];
        const char* Vc = (const char*)&Vs[cur][0];

        f32x4 sc[4];
#pragma unroll
        for (int kb = 0; kb < 4; ++kb) {    // S^T[key][q], log2 domain
            const char* kr = Kc + (kb * 16 + l15) * 128;
            bf16x8 ak0 = *(const bf16x8*)(kr + ((g * 16) ^ r7));
            bf16x8 ak1 = *(const bf16x8*)(kr + ((64 + g * 16) ^ r7));
            f32x4 c = zero;
            c = __builtin_amdgcn_mfma_f32_16x16x32_bf16(ak0, bq0, c, 0, 0, 0);
            c = __builtin_amdgcn_mfma_f32_16x16x32_bf16(ak1, bq1, c, 0, 0, 0);
            sc[kb] = c;
        }
        if (half && t == ntot - 1) {        // causal mask, last tile only
            const int t0 = t * 64;
#pragma unroll
            for (int kb = 0; kb < 4; ++kb)
#pragma unroll
                for (int i = 0; i < 4; ++i)
                    if (t0 + kb * 16 + g * 4 + i > PDIM + q) sc[kb][i] = -1e30f;
        }
        unsigned pw[8];
#pragma unroll
        for (int kb = 0; kb < 4; ++kb) {    // P = exp2(s), no max needed
            float p0 = fexp2(sc[kb][0]);
            float p1 = fexp2(sc[kb][1]);
            float p2 = fexp2(sc[kb][2]);
            float p3 = fexp2(sc[kb][3]);
            asm("v_cvt_pk_bf16_f32 %0, %1, %2"
                : "=v"(pw[2 * kb]) : "v"(p0), "v"(p1));
            asm("v_cvt_pk_bf16_f32 %0, %1, %2"
                : "=v"(pw[2 * kb + 1]) : "v"(p2), "v"(p3));
        }
#pragma unroll
        for (int kb = 0; kb < 4; ++kb) {    // P[q][key], 8B, swizzled col
            u32x2 pk2 = {pw[2 * kb], pw[2 * kb + 1]};
            *(u32x2*)(myP + l15 * 128 + ((kb * 32 + g * 8) ^ pswz)) = pk2;
        }
        asm volatile("s_waitcnt lgkmcnt(0)" ::: "memory");
        __builtin_amdgcn_sched_barrier(0);
        bf16x8 bp0 = *(const bf16x8*)(myP + l15 * 128 + ((g * 16) ^ pswz));
        bf16x8 bp1 = *(const bf16x8*)(myP + l15 * 128 + ((64 + g * 16) ^ pswz));
        lsum = __builtin_amdgcn_mfma_f32_16x16x32_bf16(vones, bp0, lsum, 0, 0, 0);
        lsum = __builtin_amdgcn_mfma_f32_16x16x32_bf16(vones, bp1, lsum, 0, 0, 0);
#pragma unroll
        for (int d = 0; d < 4; ++d) {       // O^T[d][q] += V^T . P^T
            const char* vr = Vc + (d * 16 + l15) * 128;
            bf16x8 av0 = *(const bf16x8*)(vr + ((g * 16) ^ r7));
            bf16x8 av1 = *(const bf16x8*)(vr + ((64 + g * 16) ^ r7));
            o[d] = __builtin_amdgcn_mfma_f32_16x16x32_bf16(av0, bp0, o[d], 0, 0, 0);
            o[d] = __builtin_amdgcn_mfma_f32_16x16x32_bf16(av1, bp1, o[d], 0, 0, 0);
        }
        __syncthreads();                    // drains prefetch + compute
        cur ^= 1;
    }

    // store partials: po[half][h][q][64d] f32, pl[half*16+h][q]
    float* pob = (half ? po1 : po0) + (((h * SDIM) + q) << 6);
#pragma unroll
    for (int d = 0; d < 4; ++d)
        *(f32x4*)(pob + d * 16 + g * 4) = o[d];
    if (g == 0) pl[(half * 16 + h) * SDIM + q] = lsum[0];
}

// --------------------------- merge partials --------------------------------
// aout[q][e] = bf16((o0+o1) / (l0+l1));  e = h*64+d.
__global__ __launch_bounds__(256) void k_merge(
    const float* __restrict__ po0, const float* __restrict__ po1,
    const float* __restrict__ pl, short* __restrict__ aout) {
    int idx = (blockIdx.x * 256 + threadIdx.x) * 4;   // over S*E = 2M
    int q = idx >> 10;
    int e = idx & 1023;
    int h = e >> 6, d = e & 63;
    int pbase = ((h * SDIM + q) << 6) + d;
    f32x4 a = *(const f32x4*)(po0 + pbase);
    f32x4 b = *(const f32x4*)(po1 + pbase);
    float inv = 1.0f / (pl[h * SDIM + q] + pl[(16 + h) * SDIM + q]);
    unsigned lo = f2bf((a[0] + b[0]) * inv) | ((unsigned)f2bf((a[1] + b[1]) * inv) << 16);
    unsigned hi = f2bf((a[2] + b[2]) * inv) | ((unsigned)f2bf((a[3] + b[3]) * inv) << 16);
    u32x2 p = {lo, hi};
    *(u32x2*)(aout + idx) = p;
}

// --------------------------- launch ----------------------------------------

extern "C" void kernel_launch(void* const* d_in, const int* in_sizes, int n_in,
                              void* d_out, int out_size, void* d_ws, size_t ws_size,
                              hipStream_t stream) {
    const float* x          = (const float*)d_in[0];
    const float* past_key   = (const float*)d_in[1];
    const float* past_value = (const float*)d_in[2];
    // d_in[3] = mask: recomputed analytically (k <= q + P)
    const float* c_attn_w   = (const float*)d_in[4];
    const float* c_attn_b   = (const float*)d_in[5];
    const float* c_proj_w   = (const float*)d_in[6];
    const float* c_proj_b   = (const float*)d_in[7];

    float* out_a  = (float*)d_out;
    float* pk_out = out_a + (size_t)SDIM * EDIM;           // present[0]
    float* pv_out = pk_out + (size_t)HNUM * TDIM * DDIM;   // present[1]

    char* ws = (char*)d_ws;
    short* xb     = (short*)(ws);                // 4 MB   (dead after gemm0)
    short* wqkvt  = (short*)(ws + (4u  << 20));  // 6 MB   (dead after gemm0)
    float* po0    = (float*)(ws);                // 8 MB   (overlay xb+wqkvt)
    float* pl     = (float*)(ws + 8912896u);     // 256 KB @8.5MB (overlay)
    short* wprojt = (short*)(ws + (10u << 20));  // 2 MB
    short* q_ws   = (short*)(ws + (12u << 20));  // 4 MB   (dead after attn)
    short* aout   = (short*)(ws + (12u << 20));  // 4 MB   (overlay q_ws)
    short* Kb     = (short*)(ws + (16u << 20));  // 8 MB   [H][T][D]
    short* Vt     = (short*)(ws + (24u << 20));  // 8 MB   [H][D][T]
    float* po1    = out_a;                       // 8 MB   (a region, dead
                                                 //         until gemm1 writes)

    k_prep<<<10240, 256, 0, stream>>>(x, past_key, past_value, c_attn_w,
                                      c_proj_w, xb, wqkvt, wprojt, Kb, Vt,
                                      pk_out, pv_out);

    k_gemm<0><<<dim3(24, 16), 256, 0, stream>>>(
        xb, wqkvt, c_attn_b, EDIM, q_ws, Kb, Vt, pk_out, pv_out,
        (float*)nullptr, 3 * EDIM);

    k_attn_part<<<1024, 256, 0, stream>>>(q_ws, Kb, Vt, po0, po1, pl);

    k_merge<<<2048, 256, 0, stream>>>(po0, po1, pl, aout);

    k_gemm<1><<<dim3(8, 16), 256, 0, stream>>>(
        aout, wprojt, c_proj_b, EDIM,
        (short*)nullptr, (short*)nullptr, (short*)nullptr,
        (float*)nullptr, (float*)nullptr, out_a, EDIM);
}